// Round 1
// baseline (1540.131 us; speedup 1.0000x reference)
//
#include <hip/hip_runtime.h>
#include <hip/hip_bf16.h>

typedef __hip_bfloat16 bf16;
typedef __attribute__((ext_vector_type(8))) short bf16x8;
typedef __attribute__((ext_vector_type(4))) float f32x4;

#define EPI_F32 0
#define EPI_BF16 1
#define EPI_BF16_T 2
#define EPI_F32_RES 3
#define EPI_BF16_GELU 4
#define EPI_BF16_MUL 5

__device__ __forceinline__ void gload_lds16(const void* g, void* l) {
  __builtin_amdgcn_global_load_lds(
      (const __attribute__((address_space(1))) unsigned int*)g,
      (__attribute__((address_space(3))) unsigned int*)l, 16, 0, 0);
}

// C = A(MxK, row-major, lda) * B^T where B is stored [N x K] row-major (ldb).
// 128x128 tile, BK=64, 4 waves (2x2), each wave 64x64 = 4x4 frags of 16x16x32 MFMA.
// LDS tiles XOR-swizzled: chunk ^= (row&7); global source pre-swizzled to match
// (global_load_lds writes linearly: wave base + lane*16).
template<int EPI>
__global__ __launch_bounds__(256, 3) void gemm_k(
    const bf16* __restrict__ A, const bf16* __restrict__ B,
    void* __restrict__ Cv, const void* __restrict__ auxv,
    int M, int N, int K, int lda, int ldb,
    long sAz, long sBz, long sCz, int batchM)
{
  __shared__ bf16 As[128 * 64];
  __shared__ bf16 Bs[128 * 64];

  const int z = blockIdx.z;
  A += (size_t)z * (size_t)sAz;
  B += (size_t)z * (size_t)sBz;

  const int brow = blockIdx.y * 128;
  const int bcol = blockIdx.x * 128;
  const int t = threadIdx.x;
  const int w = t >> 6;
  const int lane = t & 63;
  const int wr = (w >> 1) * 64;
  const int wc = (w & 1) * 64;
  const int l15 = lane & 15;
  const int lg = lane >> 4;

  f32x4 acc[4][4];
#pragma unroll
  for (int i = 0; i < 4; ++i)
#pragma unroll
    for (int j = 0; j < 4; ++j) {
      f32x4 zz = {0.f, 0.f, 0.f, 0.f};
      acc[i][j] = zz;
    }

  for (int kt = 0; kt < K; kt += 64) {
    // stage A,B tiles: 16KB each; per issue a wave moves 1KB (64 lanes x 16B)
#pragma unroll
    for (int i = 0; i < 4; ++i) {
      const int bslot = (i * 4 + w) * 64;      // wave-uniform LDS base slot
      const int slot = bslot + lane;           // 16B slot: row=slot>>3, chunk=slot&7
      const int r = slot >> 3;
      const int cs = (slot & 7) ^ (r & 7);     // pre-swizzled global chunk
      gload_lds16(A + (size_t)(brow + r) * lda + kt + cs * 8, (char*)As + bslot * 16);
      gload_lds16(B + (size_t)(bcol + r) * ldb + kt + cs * 8, (char*)Bs + bslot * 16);
    }
    __syncthreads();
#pragma unroll
    for (int ks = 0; ks < 2; ++ks) {
      bf16x8 av[4], bv[4];
#pragma unroll
      for (int mi = 0; mi < 4; ++mi) {
        const int r = wr + mi * 16 + l15;
        const int ch = (ks * 4 + lg) ^ (r & 7);
        av[mi] = *(const bf16x8*)((const char*)As + r * 128 + ch * 16);
      }
#pragma unroll
      for (int ni = 0; ni < 4; ++ni) {
        const int r = wc + ni * 16 + l15;
        const int ch = (ks * 4 + lg) ^ (r & 7);
        bv[ni] = *(const bf16x8*)((const char*)Bs + r * 128 + ch * 16);
      }
#pragma unroll
      for (int mi = 0; mi < 4; ++mi)
#pragma unroll
        for (int ni = 0; ni < 4; ++ni)
          acc[mi][ni] = __builtin_amdgcn_mfma_f32_16x16x32_bf16(av[mi], bv[ni], acc[mi][ni], 0, 0, 0);
    }
    __syncthreads();
  }

  // Epilogue. C/D frag: col = lane&15, row = (lane>>4)*4 + reg  [m89-verified]
  if constexpr (EPI == EPI_BF16_T) {
    // write C^T: out[(m/batchM)][n][m%batchM], 4 regs are m-contiguous
    bf16* C = (bf16*)Cv + (size_t)z * (size_t)sCz;
#pragma unroll
    for (int mi = 0; mi < 4; ++mi) {
      const int mbase = brow + wr + mi * 16 + lg * 4;
      const int bi = mbase / batchM;
      const int ms = mbase - bi * batchM;
      const size_t base = (size_t)bi * (size_t)N * (size_t)batchM + (size_t)ms;
#pragma unroll
      for (int ni = 0; ni < 4; ++ni) {
        const int n = bcol + wc + ni * 16 + l15;
        bf16* p = C + base + (size_t)n * (size_t)batchM;
#pragma unroll
        for (int r = 0; r < 4; ++r) p[r] = __float2bfloat16(acc[mi][ni][r]);
      }
    }
  } else {
#pragma unroll
    for (int mi = 0; mi < 4; ++mi) {
#pragma unroll
      for (int r = 0; r < 4; ++r) {
        const int m = brow + wr + mi * 16 + lg * 4 + r;
#pragma unroll
        for (int ni = 0; ni < 4; ++ni) {
          const int n = bcol + wc + ni * 16 + l15;
          const size_t idx = (size_t)m * (size_t)N + (size_t)n;
          float v = acc[mi][ni][r];
          if constexpr (EPI == EPI_F32) {
            ((float*)Cv + (size_t)z * (size_t)sCz)[idx] = v;
          } else if constexpr (EPI == EPI_F32_RES) {
            ((float*)Cv)[idx] = v + ((const float*)auxv)[idx];
          } else if constexpr (EPI == EPI_BF16) {
            ((bf16*)Cv)[idx] = __float2bfloat16(v);
          } else if constexpr (EPI == EPI_BF16_GELU) {
            v = 0.5f * v * (1.0f + erff(v * 0.70710678118654752f));
            ((bf16*)Cv)[idx] = __float2bfloat16(v);
          } else if constexpr (EPI == EPI_BF16_MUL) {
            v = v * __bfloat162float(((const bf16*)auxv)[idx]);
            ((bf16*)Cv)[idx] = __float2bfloat16(v);
          }
        }
      }
    }
  }
}

// LayerNorm over rows of 2048 fp32 -> bf16  (biased var, eps=1e-5, weight, no bias)
__global__ __launch_bounds__(256) void ln_k(const float* __restrict__ x,
                                            const float* __restrict__ w,
                                            bf16* __restrict__ out) {
  const int row = blockIdx.x;
  const int t = threadIdx.x;
  const float* xr = x + (size_t)row * 2048;
  float4 a = ((const float4*)xr)[2 * t];
  float4 b = ((const float4*)xr)[2 * t + 1];
  float s = a.x + a.y + a.z + a.w + b.x + b.y + b.z + b.w;
  float ss = a.x * a.x + a.y * a.y + a.z * a.z + a.w * a.w +
             b.x * b.x + b.y * b.y + b.z * b.z + b.w * b.w;
#pragma unroll
  for (int o = 1; o < 64; o <<= 1) { s += __shfl_xor(s, o); ss += __shfl_xor(ss, o); }
  __shared__ float ps[4], pss[4];
  if ((t & 63) == 0) { ps[t >> 6] = s; pss[t >> 6] = ss; }
  __syncthreads();
  s = ps[0] + ps[1] + ps[2] + ps[3];
  ss = pss[0] + pss[1] + pss[2] + pss[3];
  const float mean = s * (1.0f / 2048.0f);
  const float var = ss * (1.0f / 2048.0f) - mean * mean;
  const float rstd = rsqrtf(var + 1e-5f);
  float4 wa = ((const float4*)w)[2 * t];
  float4 wb = ((const float4*)w)[2 * t + 1];
  bf16* o8 = out + (size_t)row * 2048 + (size_t)t * 8;
  o8[0] = __float2bfloat16((a.x - mean) * rstd * wa.x);
  o8[1] = __float2bfloat16((a.y - mean) * rstd * wa.y);
  o8[2] = __float2bfloat16((a.z - mean) * rstd * wa.z);
  o8[3] = __float2bfloat16((a.w - mean) * rstd * wa.w);
  o8[4] = __float2bfloat16((b.x - mean) * rstd * wb.x);
  o8[5] = __float2bfloat16((b.y - mean) * rstd * wb.y);
  o8[6] = __float2bfloat16((b.z - mean) * rstd * wb.z);
  o8[7] = __float2bfloat16((b.w - mean) * rstd * wb.w);
}

// softmax over rows of 2048 fp32 (scaled by 1/8) -> bf16 probabilities
__global__ __launch_bounds__(256) void softmax_k(const float* __restrict__ sc,
                                                 bf16* __restrict__ o) {
  const int row = blockIdx.x;
  const int t = threadIdx.x;
  const float* sr = sc + (size_t)row * 2048;
  float4 a = ((const float4*)sr)[2 * t];
  float4 b = ((const float4*)sr)[2 * t + 1];
  float v[8] = {a.x, a.y, a.z, a.w, b.x, b.y, b.z, b.w};
  float m = -1e30f;
#pragma unroll
  for (int i = 0; i < 8; ++i) { v[i] *= 0.125f; m = fmaxf(m, v[i]); }
#pragma unroll
  for (int o2 = 1; o2 < 64; o2 <<= 1) m = fmaxf(m, __shfl_xor(m, o2));
  __shared__ float red[4];
  if ((t & 63) == 0) red[t >> 6] = m;
  __syncthreads();
  m = fmaxf(fmaxf(red[0], red[1]), fmaxf(red[2], red[3]));
  float sum = 0.f;
#pragma unroll
  for (int i = 0; i < 8; ++i) { v[i] = __expf(v[i] - m); sum += v[i]; }
#pragma unroll
  for (int o2 = 1; o2 < 64; o2 <<= 1) sum += __shfl_xor(sum, o2);
  __syncthreads();
  if ((t & 63) == 0) red[t >> 6] = sum;
  __syncthreads();
  sum = red[0] + red[1] + red[2] + red[3];
  const float inv = 1.0f / sum;
  bf16* po = o + (size_t)row * 2048 + (size_t)t * 8;
#pragma unroll
  for (int i = 0; i < 8; ++i) po[i] = __float2bfloat16(v[i] * inv);
}

// fp32 [K][N] -> bf16 [N][K]  (LDS-tiled transpose + downconvert)
__global__ __launch_bounds__(256) void transp_k(const float* __restrict__ in,
                                                bf16* __restrict__ out,
                                                int K, int N) {
  __shared__ float tile[32][33];
  const int bn = blockIdx.x * 32;
  const int bk = blockIdx.y * 32;
  const int tx = threadIdx.x;
  const int ty = threadIdx.y;
#pragma unroll
  for (int i = 0; i < 32; i += 8)
    tile[ty + i][tx] = in[(size_t)(bk + ty + i) * N + bn + tx];
  __syncthreads();
#pragma unroll
  for (int i = 0; i < 32; i += 8)
    out[(size_t)(bn + ty + i) * K + bk + tx] = __float2bfloat16(tile[tx][ty + i]);
}

extern "C" void kernel_launch(void* const* d_in, const int* in_sizes, int n_in,
                              void* d_out, int out_size, void* d_ws, size_t ws_size,
                              hipStream_t stream) {
  (void)in_sizes; (void)n_in; (void)out_size; (void)ws_size;
  const float* x   = (const float*)d_in[0];
  const float* lnw = (const float*)d_in[1];
  const float* w_q = (const float*)d_in[2];
  const float* w_k = (const float*)d_in[3];
  const float* w_v = (const float*)d_in[4];
  const float* w_o = (const float*)d_in[5];
  const float* w_g = (const float*)d_in[6];
  const float* w_u = (const float*)d_in[7];
  const float* w_d = (const float*)d_in[8];
  float* out = (float*)d_out;

  const int E = 2048, F = 8192;
  const size_t MB = 1024ull * 1024ull;
  char* ws = (char*)d_ws;

  // ---- workspace layout (288 MB total, regions reused across phases) ----
  bf16* wq_t = (bf16*)(ws + 0 * MB);    // 8MB   [E][E]  = w_q^T
  bf16* wk_t = (bf16*)(ws + 8 * MB);    // 8MB
  bf16* wv_t = (bf16*)(ws + 16 * MB);   // 8MB
  bf16* wo_t = (bf16*)(ws + 24 * MB);   // 8MB
  bf16* wg_t = (bf16*)(ws + 32 * MB);   // 32MB  [F][E] = w_gate^T
  bf16* wu_t = (bf16*)(ws + 64 * MB);   // 32MB
  bf16* wd_t = (bf16*)(ws + 96 * MB);   // 32MB  [E][F] = w_down^T
  // R1 (32MB): h (bf16) -> scores (fp32) -> h2 (bf16)
  bf16*  h      = (bf16*)(ws + 128 * MB);
  float* scores = (float*)(ws + 128 * MB);
  bf16*  h2     = (bf16*)(ws + 128 * MB);
  // R2 (32MB): qt [2][E][S] -> attnT [2][S][E]
  bf16*  qt    = (bf16*)(ws + 160 * MB);
  bf16*  attnT = (bf16*)(ws + 160 * MB);
  // R3 (32MB): kt [2][E][S]... kt is 32MB; weights(16MB) and gate-chunk(32MB) reuse it later
  bf16*  kt  = (bf16*)(ws + 192 * MB);
  bf16*  wts = (bf16*)(ws + 192 * MB);
  bf16*  gc  = (bf16*)(ws + 192 * MB);
  // R4 (64MB): vm [2][S][E] (32MB) -> x2 fp32 (64MB)
  bf16*  vm = (bf16*)(ws + 224 * MB);
  float* x2 = (float*)(ws + 224 * MB);

  dim3 blk(256), tb(32, 8);

  // weights -> bf16 transposed
  transp_k<<<dim3(E / 32, E / 32), tb, 0, stream>>>(w_q, wq_t, E, E);
  transp_k<<<dim3(E / 32, E / 32), tb, 0, stream>>>(w_k, wk_t, E, E);
  transp_k<<<dim3(E / 32, E / 32), tb, 0, stream>>>(w_v, wv_t, E, E);
  transp_k<<<dim3(E / 32, E / 32), tb, 0, stream>>>(w_o, wo_t, E, E);
  transp_k<<<dim3(F / 32, E / 32), tb, 0, stream>>>(w_g, wg_t, E, F);
  transp_k<<<dim3(F / 32, E / 32), tb, 0, stream>>>(w_u, wu_t, E, F);
  transp_k<<<dim3(E / 32, F / 32), tb, 0, stream>>>(w_d, wd_t, F, E);

  // LN1: x -> h (bf16)
  ln_k<<<8192, blk, 0, stream>>>(x, lnw, h);

  // q,k projections written transposed per batch: qt[b][e][s]; v natural: vm[b*s][f]
  gemm_k<EPI_BF16_T><<<dim3(16, 64, 1), blk, 0, stream>>>(h, wq_t, qt, nullptr,
      8192, 2048, 2048, 2048, 2048, 0, 0, 0, 4096);
  gemm_k<EPI_BF16_T><<<dim3(16, 64, 1), blk, 0, stream>>>(h, wk_t, kt, nullptr,
      8192, 2048, 2048, 2048, 2048, 0, 0, 0, 4096);
  gemm_k<EPI_BF16><<<dim3(16, 64, 1), blk, 0, stream>>>(h, wv_t, vm, nullptr,
      8192, 2048, 2048, 2048, 2048, 0, 0, 0, 1);

  // scores[b][e][f] = sum_s qt[b][e][s] kt[b][f][s]   (fp32)
  gemm_k<EPI_F32><<<dim3(16, 16, 2), blk, 0, stream>>>(qt, kt, scores, nullptr,
      2048, 2048, 4096, 4096, 4096, (long)2048 * 4096, (long)2048 * 4096,
      (long)2048 * 2048, 1);

  // softmax over f (scale 1/8) -> bf16 weights
  softmax_k<<<4096, blk, 0, stream>>>(scores, wts);

  // attn[b][e][s] = wts[b] @ vm[b]^T  -> written transposed: attnT[b][s][e]
  gemm_k<EPI_BF16_T><<<dim3(32, 16, 2), blk, 0, stream>>>(wts, vm, attnT, nullptr,
      2048, 4096, 2048, 2048, 2048, (long)2048 * 2048, (long)4096 * 2048,
      (long)4096 * 2048, 2048);

  // x2 = attnT @ w_o + x   (fp32)
  gemm_k<EPI_F32_RES><<<dim3(16, 64, 1), blk, 0, stream>>>(attnT, wo_t, x2, x,
      8192, 2048, 2048, 2048, 2048, 0, 0, 0, 1);

  // LN2 (same ln weight): x2 -> h2 (bf16)
  ln_k<<<8192, blk, 0, stream>>>(x2, lnw, h2);

  // FFN in 4 chunks of F (keeps workspace small): gate->gelu, up*gate, down+=
  for (int c = 0; c < 4; ++c) {
    gemm_k<EPI_BF16_GELU><<<dim3(16, 64, 1), blk, 0, stream>>>(
        h2, wg_t + (size_t)c * 2048 * 2048, gc, nullptr,
        8192, 2048, 2048, 2048, 2048, 0, 0, 0, 1);
    gemm_k<EPI_BF16_MUL><<<dim3(16, 64, 1), blk, 0, stream>>>(
        h2, wu_t + (size_t)c * 2048 * 2048, gc, gc,
        8192, 2048, 2048, 2048, 2048, 0, 0, 0, 1);
    gemm_k<EPI_F32_RES><<<dim3(16, 64, 1), blk, 0, stream>>>(
        gc, wd_t + (size_t)c * 2048, out,
        (c == 0 ? (const void*)x2 : (const void*)out),
        8192, 2048, 2048, 2048, 8192, 0, 0, 0, 1);
  }
}

// Round 2
// 1425.942 us; speedup vs baseline: 1.0801x; 1.0801x over previous
//
#include <hip/hip_runtime.h>
#include <hip/hip_bf16.h>

typedef __hip_bfloat16 bf16;
typedef __attribute__((ext_vector_type(8))) short bf16x8;
typedef __attribute__((ext_vector_type(4))) float f32x4;

#define EPI_BF16 1
#define EPI_BF16_T 2
#define EPI_F32_RES 3
#define EPI_BF16_GELU 4
#define EPI_BF16_MUL 5
#define EPI_F32_KSPLIT 6

__device__ __forceinline__ void gload_lds16(const bf16* g, char* l) {
  __builtin_amdgcn_global_load_lds(
      (const __attribute__((address_space(1))) unsigned int*)g,
      (__attribute__((address_space(3))) unsigned int*)l, 16, 0, 0);
}

#define SCHED0() __builtin_amdgcn_sched_barrier(0)

// 16 MFMAs: one C-quadrant (mi = 2Q,2Q+1) x all ni x both k-steps. setprio-wrapped (T5).
#define MFQ(Q, AR)                                                                 \
  do {                                                                             \
    __builtin_amdgcn_s_setprio(1);                                                 \
    _Pragma("unroll") for (int j_ = 0; j_ < 2; ++j_)                               \
        _Pragma("unroll") for (int ni_ = 0; ni_ < 4; ++ni_)                        \
            _Pragma("unroll") for (int ks_ = 0; ks_ < 2; ++ks_)                    \
                acc[(Q) * 2 + j_][ni_] = __builtin_amdgcn_mfma_f32_16x16x32_bf16(  \
                    AR[j_][ks_], bfr[ni_][ks_], acc[(Q) * 2 + j_][ni_], 0, 0, 0);  \
    __builtin_amdgcn_s_setprio(0);                                                 \
  } while (0)

// C = A(MxK,row-major,lda) * B^T, B stored [N x K] row-major (ldb).
// 256x256 tile, BK=64, 8 waves (2M x 4N), per-wave 128x64 = 8x4 frags of 16x16x32.
// LDS 128KB double-buffered; XOR-swizzled (chunk ^= row&7) staging + reads.
// Counted-vmcnt pipeline: tile t+1's 8 loads stay in flight across tile t's compute.
template<int EPI>
__global__ __launch_bounds__(512, 2) void gemm256_k(
    const bf16* __restrict__ A, const bf16* __restrict__ B,
    void* __restrict__ Cv, const void* __restrict__ auxv,
    int N, int K, int lda, int ldb,
    long sAz, long sBz, long sCz, int batchM)
{
  __shared__ bf16 lds[4 * 256 * 64];  // As0|Bs0|As1|Bs1, 32KB each
  char* const As0 = (char*)lds;
  char* const Bs0 = As0 + 32768;
  char* const As1 = Bs0 + 32768;
  char* const Bs1 = As1 + 32768;

  // T1: XCD-aware swizzle over the flattened grid (all grids are %8==0)
  const int gx = gridDim.x, gy = gridDim.y;
  int lid = (blockIdx.z * gy + blockIdx.y) * gx + blockIdx.x;
  const int cpx = (gx * gy * gridDim.z) >> 3;
  lid = (lid & 7) * cpx + (lid >> 3);
  const int bx = lid % gx;
  const int rem = lid / gx;
  const int by = rem % gy;
  const int z = rem / gy;

  int zb = z, part = 0;
  if constexpr (EPI == EPI_F32_KSPLIT) { zb = z & 1; part = z >> 1; }
  A += (size_t)zb * (size_t)sAz + (size_t)part * (size_t)batchM;
  B += (size_t)zb * (size_t)sBz + (size_t)part * (size_t)batchM;

  const int brow = by * 256, bcol = bx * 256;
  const int t = threadIdx.x;
  const int w = t >> 6, lane = t & 63;
  const int wrow = (w >> 2) * 128;  // 2 M-waves
  const int wcol = (w & 3) * 64;    // 4 N-waves
  const int l15 = lane & 15, lg = lane >> 4;

  f32x4 acc[8][4];
#pragma unroll
  for (int i = 0; i < 8; ++i)
#pragma unroll
    for (int j = 0; j < 4; ++j) {
      f32x4 zz = {0.f, 0.f, 0.f, 0.f};
      acc[i][j] = zz;
    }

  // stage one K-tile (A 256x64 + B 256x64): 8 gload_lds of 16B per thread
  auto STAGE = [&](int kk, char* Ad, char* Bd) {
#pragma unroll
    for (int i = 0; i < 4; ++i) {
      const int bslot = (i * 8 + w) * 64;   // wave-uniform 16B-slot base
      const int slot = bslot + lane;        // row = slot>>3, chunk = slot&7
      const int r = slot >> 3;
      const int cs = (slot & 7) ^ (r & 7);  // pre-swizzled global chunk (rule #21)
      gload_lds16(A + (size_t)(brow + r) * lda + kk + cs * 8, Ad + bslot * 16);
      gload_lds16(B + (size_t)(bcol + r) * ldb + kk + cs * 8, Bd + bslot * 16);
    }
  };
  auto rdA = [&](const char* Ab, int mi, int ks) {
    const int r = wrow + mi * 16 + l15;
    return *(const bf16x8*)(Ab + ((r * 8 + ((ks * 4 + lg) ^ (r & 7))) << 4));
  };
  auto rdB = [&](const char* Bb, int ni, int ks) {
    const int r = wcol + ni * 16 + l15;
    return *(const bf16x8*)(Bb + ((r * 8 + ((ks * 4 + lg) ^ (r & 7))) << 4));
  };

  STAGE(0, As0, Bs0);
  STAGE(64, As1, Bs1);  // K >= 128 for all our shapes

  const int NT = K >> 6;
  bf16x8 bfr[4][2], aA[2][2], aB[2][2];

  for (int tt = 0; tt < NT; ++tt) {
    const char* Ar = (tt & 1) ? As1 : As0;
    const char* Br = (tt & 1) ? Bs1 : Bs0;
    char* Aw = (tt & 1) ? As1 : As0;
    char* Bw = (tt & 1) ? Bs1 : Bs0;

    // tile tt's loads done after this wait+barrier; tile tt+1's 8 stay in flight (T4)
    if (tt + 1 < NT) { asm volatile("s_waitcnt vmcnt(8)" ::: "memory"); }
    else             { asm volatile("s_waitcnt vmcnt(0)" ::: "memory"); }
    SCHED0();
    __builtin_amdgcn_s_barrier();
    SCHED0();

    bfr[0][0] = rdB(Br, 0, 0); bfr[0][1] = rdB(Br, 0, 1);
    bfr[1][0] = rdB(Br, 1, 0); bfr[1][1] = rdB(Br, 1, 1);
    bfr[2][0] = rdB(Br, 2, 0); bfr[2][1] = rdB(Br, 2, 1);
    bfr[3][0] = rdB(Br, 3, 0); bfr[3][1] = rdB(Br, 3, 1);
    aA[0][0] = rdA(Ar, 0, 0); aA[0][1] = rdA(Ar, 0, 1);
    aA[1][0] = rdA(Ar, 1, 0); aA[1][1] = rdA(Ar, 1, 1);
    aB[0][0] = rdA(Ar, 2, 0); aB[0][1] = rdA(Ar, 2, 1);
    aB[1][0] = rdA(Ar, 3, 0); aB[1][1] = rdA(Ar, 3, 1);
    MFQ(0, aA);
    aA[0][0] = rdA(Ar, 4, 0); aA[0][1] = rdA(Ar, 4, 1);
    aA[1][0] = rdA(Ar, 5, 0); aA[1][1] = rdA(Ar, 5, 1);
    MFQ(1, aB);
    aB[0][0] = rdA(Ar, 6, 0); aB[0][1] = rdA(Ar, 6, 1);
    aB[1][0] = rdA(Ar, 7, 0); aB[1][1] = rdA(Ar, 7, 1);
    MFQ(2, aA);
    // all of this wave's reads of buf[tt&1] complete before the barrier,
    // so after it every wave may overwrite the buffer with tile tt+2
    asm volatile("s_waitcnt lgkmcnt(0)" ::: "memory");
    SCHED0();
    __builtin_amdgcn_s_barrier();
    SCHED0();
    if (tt + 2 < NT) STAGE((tt + 2) * 64, Aw, Bw);
    MFQ(3, aB);  // overlaps the freshly-issued stage loads
  }

  // Epilogue. C/D frag: col = lane&15, row = (lane>>4)*4 + reg  [m89-verified]
  if constexpr (EPI == EPI_BF16_T) {
    bf16* C = (bf16*)Cv + (size_t)zb * (size_t)sCz;
#pragma unroll
    for (int mi = 0; mi < 8; ++mi) {
      const int mbase = brow + wrow + mi * 16 + lg * 4;
      const int bi = mbase / batchM;
      const int ms = mbase - bi * batchM;
      const size_t base = (size_t)bi * (size_t)N * (size_t)batchM + (size_t)ms;
#pragma unroll
      for (int ni = 0; ni < 4; ++ni) {
        const int n = bcol + wcol + ni * 16 + l15;
        union { short4 s; short h[4]; } u;
#pragma unroll
        for (int r = 0; r < 4; ++r) {
          bf16 bv = __float2bfloat16(acc[mi][ni][r]);
          u.h[r] = *(short*)&bv;
        }
        *(short4*)(C + base + (size_t)n * (size_t)batchM) = u.s;
      }
    }
  } else {
#pragma unroll
    for (int mi = 0; mi < 8; ++mi) {
#pragma unroll
      for (int r = 0; r < 4; ++r) {
        const int m = brow + wrow + mi * 16 + lg * 4 + r;
#pragma unroll
        for (int ni = 0; ni < 4; ++ni) {
          const int n = bcol + wcol + ni * 16 + l15;
          const size_t idx = (size_t)m * (size_t)N + (size_t)n;
          float v = acc[mi][ni][r];
          if constexpr (EPI == EPI_F32_KSPLIT) {
            float* C = (part ? (float*)auxv : (float*)Cv) + (size_t)zb * (size_t)sCz;
            C[idx] = v;
          } else if constexpr (EPI == EPI_F32_RES) {
            ((float*)Cv)[idx] = v + ((const float*)auxv)[idx];
          } else if constexpr (EPI == EPI_BF16) {
            ((bf16*)Cv)[idx] = __float2bfloat16(v);
          } else if constexpr (EPI == EPI_BF16_GELU) {
            v = 0.5f * v * (1.0f + erff(v * 0.70710678118654752f));
            ((bf16*)Cv)[idx] = __float2bfloat16(v);
          } else if constexpr (EPI == EPI_BF16_MUL) {
            v = v * __bfloat162float(((const bf16*)auxv)[idx]);
            ((bf16*)Cv)[idx] = __float2bfloat16(v);
          }
        }
      }
    }
  }
}

// LayerNorm over rows of 2048 fp32 -> bf16 (biased var, eps=1e-5, weight, no bias)
__global__ __launch_bounds__(256) void ln_k(const float* __restrict__ x,
                                            const float* __restrict__ w,
                                            bf16* __restrict__ out) {
  const int row = blockIdx.x;
  const int t = threadIdx.x;
  const float* xr = x + (size_t)row * 2048;
  float4 a = ((const float4*)xr)[2 * t];
  float4 b = ((const float4*)xr)[2 * t + 1];
  float s = a.x + a.y + a.z + a.w + b.x + b.y + b.z + b.w;
  float ss = a.x * a.x + a.y * a.y + a.z * a.z + a.w * a.w +
             b.x * b.x + b.y * b.y + b.z * b.z + b.w * b.w;
#pragma unroll
  for (int o = 1; o < 64; o <<= 1) { s += __shfl_xor(s, o); ss += __shfl_xor(ss, o); }
  __shared__ float ps[4], pss[4];
  if ((t & 63) == 0) { ps[t >> 6] = s; pss[t >> 6] = ss; }
  __syncthreads();
  s = ps[0] + ps[1] + ps[2] + ps[3];
  ss = pss[0] + pss[1] + pss[2] + pss[3];
  const float mean = s * (1.0f / 2048.0f);
  const float var = ss * (1.0f / 2048.0f) - mean * mean;
  const float rstd = rsqrtf(var + 1e-5f);
  float4 wa = ((const float4*)w)[2 * t];
  float4 wb = ((const float4*)w)[2 * t + 1];
  bf16* o8 = out + (size_t)row * 2048 + (size_t)t * 8;
  o8[0] = __float2bfloat16((a.x - mean) * rstd * wa.x);
  o8[1] = __float2bfloat16((a.y - mean) * rstd * wa.y);
  o8[2] = __float2bfloat16((a.z - mean) * rstd * wa.z);
  o8[3] = __float2bfloat16((a.w - mean) * rstd * wa.w);
  o8[4] = __float2bfloat16((b.x - mean) * rstd * wb.x);
  o8[5] = __float2bfloat16((b.y - mean) * rstd * wb.y);
  o8[6] = __float2bfloat16((b.z - mean) * rstd * wb.z);
  o8[7] = __float2bfloat16((b.w - mean) * rstd * wb.w);
}

// softmax over rows of 2048: input = sp0 + sp1 (split-K partials), scale 1/8 -> bf16
__global__ __launch_bounds__(256) void softmax2_k(const float* __restrict__ s0,
                                                  const float* __restrict__ s1,
                                                  bf16* __restrict__ o) {
  const int row = blockIdx.x;
  const int t = threadIdx.x;
  const float* r0 = s0 + (size_t)row * 2048;
  const float* r1 = s1 + (size_t)row * 2048;
  float4 a = ((const float4*)r0)[2 * t];
  float4 b = ((const float4*)r0)[2 * t + 1];
  float4 c = ((const float4*)r1)[2 * t];
  float4 d = ((const float4*)r1)[2 * t + 1];
  float v[8] = {a.x + c.x, a.y + c.y, a.z + c.z, a.w + c.w,
                b.x + d.x, b.y + d.y, b.z + d.z, b.w + d.w};
  float m = -1e30f;
#pragma unroll
  for (int i = 0; i < 8; ++i) { v[i] *= 0.125f; m = fmaxf(m, v[i]); }
#pragma unroll
  for (int o2 = 1; o2 < 64; o2 <<= 1) m = fmaxf(m, __shfl_xor(m, o2));
  __shared__ float red[4];
  if ((t & 63) == 0) red[t >> 6] = m;
  __syncthreads();
  m = fmaxf(fmaxf(red[0], red[1]), fmaxf(red[2], red[3]));
  float sum = 0.f;
#pragma unroll
  for (int i = 0; i < 8; ++i) { v[i] = __expf(v[i] - m); sum += v[i]; }
#pragma unroll
  for (int o2 = 1; o2 < 64; o2 <<= 1) sum += __shfl_xor(sum, o2);
  __syncthreads();
  if ((t & 63) == 0) red[t >> 6] = sum;
  __syncthreads();
  sum = red[0] + red[1] + red[2] + red[3];
  const float inv = 1.0f / sum;
  bf16* po = o + (size_t)row * 2048 + (size_t)t * 8;
#pragma unroll
  for (int i = 0; i < 8; ++i) po[i] = __float2bfloat16(v[i] * inv);
}

// fp32 [K][N] -> bf16 [N][K]  (LDS-tiled transpose + downconvert)
__global__ __launch_bounds__(256) void transp_k(const float* __restrict__ in,
                                                bf16* __restrict__ out,
                                                int K, int N) {
  __shared__ float tile[32][33];
  const int bn = blockIdx.x * 32;
  const int bk = blockIdx.y * 32;
  const int tx = threadIdx.x;
  const int ty = threadIdx.y;
#pragma unroll
  for (int i = 0; i < 32; i += 8)
    tile[ty + i][tx] = in[(size_t)(bk + ty + i) * N + bn + tx];
  __syncthreads();
#pragma unroll
  for (int i = 0; i < 32; i += 8)
    out[(size_t)(bn + ty + i) * K + bk + tx] = __float2bfloat16(tile[tx][ty + i]);
}

extern "C" void kernel_launch(void* const* d_in, const int* in_sizes, int n_in,
                              void* d_out, int out_size, void* d_ws, size_t ws_size,
                              hipStream_t stream) {
  (void)in_sizes; (void)n_in; (void)out_size; (void)ws_size;
  const float* x   = (const float*)d_in[0];
  const float* lnw = (const float*)d_in[1];
  const float* w_q = (const float*)d_in[2];
  const float* w_k = (const float*)d_in[3];
  const float* w_v = (const float*)d_in[4];
  const float* w_o = (const float*)d_in[5];
  const float* w_g = (const float*)d_in[6];
  const float* w_u = (const float*)d_in[7];
  const float* w_d = (const float*)d_in[8];
  float* out = (float*)d_out;

  const int E = 2048, F = 8192;
  const size_t MB = 1024ull * 1024ull;
  char* ws = (char*)d_ws;

  // ---- workspace (288 MB, regions reused across phases) ----
  bf16* wq_t = (bf16*)(ws + 0 * MB);     // 8MB  [E][E] = w_q^T
  bf16* wk_t = (bf16*)(ws + 8 * MB);     // 8MB
  bf16* wv_t = (bf16*)(ws + 16 * MB);    // 8MB
  bf16* wo_t = (bf16*)(ws + 24 * MB);    // 8MB
  bf16* wg_t = (bf16*)(ws + 32 * MB);    // 32MB [F][E] = w_gate^T
  bf16* wu_t = (bf16*)(ws + 64 * MB);    // 32MB
  bf16* wd_t = (bf16*)(ws + 96 * MB);    // 32MB [E][F] = w_down^T
  bf16*  h   = (bf16*)(ws + 128 * MB);   // 32MB  h -> sp0 -> h2
  float* sp0 = (float*)(ws + 128 * MB);
  bf16*  h2  = (bf16*)(ws + 128 * MB);
  bf16*  qt    = (bf16*)(ws + 160 * MB); // 32MB  qt -> attnT -> gc(lo)
  bf16*  attnT = (bf16*)(ws + 160 * MB);
  bf16*  gc    = (bf16*)(ws + 160 * MB); // 64MB [160,224)
  bf16*  kt  = (bf16*)(ws + 192 * MB);   // 32MB  kt -> wts -> gc(hi)
  bf16*  wts = (bf16*)(ws + 192 * MB);
  bf16*  vm  = (bf16*)(ws + 224 * MB);   // 32MB  vm -> x2(lo)
  float* x2  = (float*)(ws + 224 * MB);  // 64MB [224,288)
  float* sp1 = (float*)(ws + 256 * MB);  // 32MB  (dead before x2 grows over it)

  dim3 blk(256), tb(32, 8), g512(512);

  transp_k<<<dim3(E / 32, E / 32), tb, 0, stream>>>(w_q, wq_t, E, E);
  transp_k<<<dim3(E / 32, E / 32), tb, 0, stream>>>(w_k, wk_t, E, E);
  transp_k<<<dim3(E / 32, E / 32), tb, 0, stream>>>(w_v, wv_t, E, E);
  transp_k<<<dim3(E / 32, E / 32), tb, 0, stream>>>(w_o, wo_t, E, E);
  transp_k<<<dim3(F / 32, E / 32), tb, 0, stream>>>(w_g, wg_t, E, F);
  transp_k<<<dim3(F / 32, E / 32), tb, 0, stream>>>(w_u, wu_t, E, F);
  transp_k<<<dim3(E / 32, F / 32), tb, 0, stream>>>(w_d, wd_t, F, E);

  ln_k<<<8192, blk, 0, stream>>>(x, lnw, h);

  // q,k written transposed per batch: qt[b][e][s]; v natural: vm[b*s][e']
  gemm256_k<EPI_BF16_T><<<dim3(8, 32, 1), g512, 0, stream>>>(h, wq_t, qt, nullptr,
      2048, 2048, 2048, 2048, 0, 0, 0, 4096);
  gemm256_k<EPI_BF16_T><<<dim3(8, 32, 1), g512, 0, stream>>>(h, wk_t, kt, nullptr,
      2048, 2048, 2048, 2048, 0, 0, 0, 4096);
  gemm256_k<EPI_BF16><<<dim3(8, 32, 1), g512, 0, stream>>>(h, wv_t, vm, nullptr,
      2048, 2048, 2048, 2048, 0, 0, 0, 1);

  // scores split-K: z = (part<<1)|batch; partial p sums s in [p*2048,(p+1)*2048)
  gemm256_k<EPI_F32_KSPLIT><<<dim3(8, 8, 4), g512, 0, stream>>>(qt, kt, sp0, sp1,
      2048, 2048, 4096, 4096, (long)2048 * 4096, (long)2048 * 4096,
      (long)2048 * 2048, 2048);

  softmax2_k<<<4096, blk, 0, stream>>>(sp0, sp1, wts);

  // attn[b][e][s] = wts[b] @ vm[b]^T -> stored transposed: attnT[b][s][e]
  gemm256_k<EPI_BF16_T><<<dim3(16, 8, 2), g512, 0, stream>>>(wts, vm, attnT, nullptr,
      4096, 2048, 2048, 2048, (long)2048 * 2048, (long)4096 * 2048,
      (long)4096 * 2048, 2048);

  // x2 = attnT @ w_o + x   (fp32)
  gemm256_k<EPI_F32_RES><<<dim3(8, 32, 1), g512, 0, stream>>>(attnT, wo_t, x2, x,
      2048, 2048, 2048, 2048, 0, 0, 0, 1);

  ln_k<<<8192, blk, 0, stream>>>(x2, lnw, h2);

  // FFN in 2 chunks of F/2=4096: gate->gelu, up*gate, down(+residual/accumulate)
  for (int c = 0; c < 2; ++c) {
    gemm256_k<EPI_BF16_GELU><<<dim3(16, 32, 1), g512, 0, stream>>>(
        h2, wg_t + (size_t)c * 4096 * 2048, gc, nullptr,
        4096, 2048, 2048, 2048, 0, 0, 0, 1);
    gemm256_k<EPI_BF16_MUL><<<dim3(16, 32, 1), g512, 0, stream>>>(
        h2, wu_t + (size_t)c * 4096 * 2048, gc, gc,
        4096, 2048, 2048, 2048, 0, 0, 0, 1);
    gemm256_k<EPI_F32_RES><<<dim3(8, 32, 1), g512, 0, stream>>>(
        gc, wd_t + (size_t)c * 4096, out,
        (c == 0 ? (const void*)x2 : (const void*)out),
        2048, 4096, 4096, 8192, 0, 0, 0, 1);
  }
}